// Round 1
// baseline (3123.802 us; speedup 1.0000x reference)
//
#include <hip/hip_runtime.h>
#include <math.h>

// Problem constants
#define NN 400
#define TPB 768          // 12 waves; waves own 2 VGPR W-tiles each; wave10 streams tile24,
                         // wave11 streams muscle tile; wave9 runs the (deferred) arm ODE
#define KP 424           // padded K stride in fp16 elems

// workspace layout (32-bit indices)
#define XRAW_OFF 1024    // 3200 floats
#define HINP_OFF 4224    // 400 floats
#define CL_OFF   4624    // 2400 floats (projected readout c from k_pre2)

#define TAU_X 0.05f
#define TAU_M 0.2f
#define A1C 0.16f
#define A2C 0.048f
#define A3C 0.045f
#define DHC 0.001f
#define L1C 0.3f
#define L2C 0.33f

typedef unsigned long long ull;
typedef _Float16 f16;
typedef _Float16 __attribute__((ext_vector_type(8))) half8;
typedef float __attribute__((ext_vector_type(4))) f32x4;

// K1: xraw[n][b] = (top_obs @ xstars_prms)[n,b] + xstars_tar[b][n]; hinp[n] = spont[n]-(W@spont)[n]
__global__ __launch_bounds__(64) void k_pre1(const float* __restrict__ topo,
        const float* __restrict__ xp, const float* __restrict__ W,
        const float* __restrict__ sp, const float* __restrict__ iw,
        const float* __restrict__ des, float* __restrict__ ws)
{
    const int n = blockIdx.x, lane = threadIdx.x;
    float a0=0,a1=0,a2=0,a3=0,a4=0,a5=0,a6=0,a7=0, ah=0;
    for (int k = lane; k < NN; k += 64) {
        float to = topo[n*NN + k];
        float wv = W[n*NN + k];
        float s  = sp[k];
        const float* xr = xp + k*8;
        a0 = fmaf(to, xr[0], a0); a1 = fmaf(to, xr[1], a1);
        a2 = fmaf(to, xr[2], a2); a3 = fmaf(to, xr[3], a3);
        a4 = fmaf(to, xr[4], a4); a5 = fmaf(to, xr[5], a5);
        a6 = fmaf(to, xr[6], a6); a7 = fmaf(to, xr[7], a7);
        ah = fmaf(wv, s, ah);
    }
    #pragma unroll
    for (int m = 1; m < 64; m <<= 1) {
        a0 += __shfl_xor(a0, m, 64); a1 += __shfl_xor(a1, m, 64);
        a2 += __shfl_xor(a2, m, 64); a3 += __shfl_xor(a3, m, 64);
        a4 += __shfl_xor(a4, m, 64); a5 += __shfl_xor(a5, m, 64);
        a6 += __shfl_xor(a6, m, 64); a7 += __shfl_xor(a7, m, 64);
        ah += __shfl_xor(ah, m, 64);
    }
    if (lane == 0) {
        float av[8] = {a0,a1,a2,a3,a4,a5,a6,a7};
        float w0 = iw[n*10 + 0], w1 = iw[n*10 + 1];
        #pragma unroll
        for (int b = 0; b < 8; ++b) {
            float j0 = des[2*b]   - 0.25f;
            float j1 = des[2*b+1] - 0.25f;
            ws[XRAW_OFF + n*8 + b] = av[b] + j0*w0 + j1*w1;
        }
        ws[HINP_OFF + n] = sp[n] - ah;
    }
}

// K2: scale s, Gram solve (fp64), Q, Cl precompute
__global__ __launch_bounds__(64) void k_pre2(const float* __restrict__ cp,
        const float* __restrict__ sp, float* __restrict__ ws)
{
    __shared__ float part[99][65];
    __shared__ float red[99];
    const int lane = threadIdx.x;
    float Sxx[36], Sxs[8], Praw[48], Ps[6];
    float Sss = 0.f;
    #pragma unroll
    for (int q = 0; q < 36; ++q) Sxx[q] = 0.f;
    #pragma unroll
    for (int q = 0; q < 8; ++q) Sxs[q] = 0.f;
    #pragma unroll
    for (int q = 0; q < 48; ++q) Praw[q] = 0.f;
    #pragma unroll
    for (int q = 0; q < 6; ++q) Ps[q] = 0.f;

    for (int n = lane; n < NN; n += 64) {
        float xr[8];
        #pragma unroll
        for (int j = 0; j < 8; ++j) xr[j] = ws[XRAW_OFF + n*8 + j];
        float s = sp[n];
        int q = 0;
        #pragma unroll
        for (int i = 0; i < 8; ++i) {
            Sxs[i] = fmaf(xr[i], s, Sxs[i]);
            #pragma unroll
            for (int j = i; j < 8; ++j) { Sxx[q] = fmaf(xr[i], xr[j], Sxx[q]); ++q; }
        }
        Sss = fmaf(s, s, Sss);
        #pragma unroll
        for (int m = 0; m < 6; ++m) {
            float cv = cp[m*NN + n];
            #pragma unroll
            for (int j = 0; j < 8; ++j) Praw[m*8+j] = fmaf(cv, xr[j], Praw[m*8+j]);
            Ps[m] = fmaf(cv, s, Ps[m]);
        }
    }
    #pragma unroll
    for (int q = 0; q < 36; ++q) part[q][lane] = Sxx[q];
    #pragma unroll
    for (int j = 0; j < 8; ++j) part[36+j][lane] = Sxs[j];
    part[44][lane] = Sss;
    #pragma unroll
    for (int q = 0; q < 48; ++q) part[45+q][lane] = Praw[q];
    #pragma unroll
    for (int m = 0; m < 6; ++m) part[93+m][lane] = Ps[m];
    __syncthreads();
    for (int q = lane; q < 99; q += 64) {
        float acc = 0.f;
        for (int l = 0; l < 64; ++l) acc += part[q][l];
        red[q] = acc;
    }
    __syncthreads();
    if (lane == 0) {
        int IDX[8][8];
        { int q = 0; for (int i = 0; i < 8; ++i) for (int j = i; j < 8; ++j) { IDX[i][j]=q; IDX[j][i]=q; ++q; } }
        float sumsq = 0.f;
        for (int i = 0; i < 8; ++i) sumsq += red[IDX[i][i]];
        double s = sqrt(128.0 / (double)sumsq);   // z = N*B*0.2^2
        double Sssd = (double)red[44];
        double G[9][9];
        for (int i = 0; i < 8; ++i)
            for (int j = 0; j < 8; ++j)
                G[i][j] = s*s*(double)red[IDX[i][j]] + s*((double)red[36+i] + (double)red[36+j]) + Sssd;
        for (int i = 0; i < 8; ++i) { G[i][8] = G[8][i] = s*(double)red[36+i] + Sssd; }
        G[8][8] = Sssd;
        double A[9][18];
        for (int i = 0; i < 9; ++i)
            for (int j = 0; j < 9; ++j) { A[i][j] = G[i][j]; A[i][9+j] = (i==j) ? 1.0 : 0.0; }
        for (int col = 0; col < 9; ++col) {
            int piv = col; double mx = fabs(A[col][col]);
            for (int r = col+1; r < 9; ++r) { double v = fabs(A[r][col]); if (v > mx) { mx = v; piv = r; } }
            if (piv != col) for (int j = 0; j < 18; ++j) { double tt = A[col][j]; A[col][j] = A[piv][j]; A[piv][j] = tt; }
            double pv = A[col][col];
            for (int j = 0; j < 18; ++j) A[col][j] /= pv;
            for (int r = 0; r < 9; ++r) if (r != col) {
                double f = A[r][col];
                for (int j = 0; j < 18; ++j) A[r][j] -= f*A[col][j];
            }
        }
        for (int m = 0; m < 6; ++m) {
            double P[9];
            for (int j = 0; j < 8; ++j) P[j] = s*(double)red[45 + m*8 + j] + (double)red[93+m];
            P[8] = (double)red[93+m];
            for (int j = 0; j < 9; ++j) {
                double qv = 0;
                for (int l = 0; l < 9; ++l) qv += P[l]*A[l][9+j];
                ws[2 + m*9 + j] = (float)qv;
            }
        }
        ws[1] = (float)s;
    }
    __syncthreads();
    // Cl[m][n] = cp[m][n] - s*(Q[m,:8].xraw[n,:]) - sp[n]*sum(Q[m,:])
    {
        float s = ws[1];
        for (int idx = lane; idx < 6*NN; idx += 64) {
            int m = idx / NN, n = idx - m*NN;
            float acc = 0.f, sq = 0.f;
            #pragma unroll
            for (int j = 0; j < 8; ++j) {
                float q = ws[2 + m*9 + j];
                acc = fmaf(q, ws[XRAW_OFF + n*8 + j], acc);
                sq += q;
            }
            sq += ws[2 + m*9 + 8];
            ws[CL_OFF + idx] = cp[idx] - s*acc - sp[n]*sq;
        }
    }
}

// A-fragment loader: W[m][k0..k0+7] fp32 -> fp16; k=400 carries h_inp (r row 400 == 1)
__device__ __forceinline__ half8 load_wfrag(const float* __restrict__ Wg,
        const float* __restrict__ ws, int m, int k0)
{
    half8 a;
    if (k0 + 8 <= 400) {
        float4 x0 = *(const float4*)(Wg + m*400 + k0);
        float4 x1 = *(const float4*)(Wg + m*400 + k0 + 4);
        a[0]=(f16)x0.x; a[1]=(f16)x0.y; a[2]=(f16)x0.z; a[3]=(f16)x0.w;
        a[4]=(f16)x1.x; a[5]=(f16)x1.y; a[6]=(f16)x1.z; a[7]=(f16)x1.w;
    } else {
        #pragma unroll
        for (int j = 0; j < 8; ++j) {
            int k = k0 + j;
            float v = 0.f;
            if (k < 400) v = Wg[m*400 + k];
            else if (k == 400) v = ws[HINP_OFF + m];
            a[j] = (f16)v;
        }
    }
    return a;
}

__device__ __forceinline__ void store_r4(f16* dst, float r0, float r1, float r2, float r3) {
    union { f16 h[4]; ull u; } pk;
    pk.h[0] = (f16)r0; pk.h[1] = (f16)r1; pk.h[2] = (f16)r2; pk.h[3] = (f16)r3;
    *(ull*)dst = pk.u;
}

// K3: whole recurrence on ONE CU via MFMA; grid = 1 block.
// B-operand broadcast: rpl keeps only the 8 REAL batch rows; lanes with
// col>=8 read the same LDS address as col-8 (free same-address broadcast,
// halves unique LDS bytes per ds_read_b128 and kills the bank conflicts).
// D cols 8-15 become duplicates of cols 0-7; all stores/consumers are
// already gated to col<8, so stored numerics are bit-identical.
// Wave 9 runs the one-step-deferred arm ODE into a 32-step LDS out-ring,
// flushed to global every 32 steps. frc is double-buffered (wave11 -> wave9).
__global__ __launch_bounds__(TPB, 3) void k_run(const int* __restrict__ Tp,
        const float* __restrict__ Wg, const float* __restrict__ sp,
        const float* __restrict__ gg, float* __restrict__ ws,
        float* __restrict__ out)
{
    __shared__ __align__(16) f16 rpl[2][8][KP];     // r planes [batch(8 real)][neuron k(424)]
    __shared__ __align__(16) f16 atile[2][16][KP];  // [0]=W rows 384..399, [1]=muscle Cl
    __shared__ float dbuf[10][48];
    __shared__ float frc[2][48];                    // double-buffered: w11 writes, w9 reads
    __shared__ float4 obuf[32][8];                  // 32-step cart out-ring

    const int tid = threadIdx.x;
    const int T = *Tp;
    const int wave = tid >> 6, lane = tid & 63;
    const int quad = lane >> 4, col = lane & 15;
    const int bcol = col & 7;                       // broadcast column for B reads
    const float s = ws[1];

    // ---- LDS init ----
    for (int idx = tid; idx < 2*8*KP; idx += TPB) ((f16*)rpl)[idx] = (f16)0.f;
    for (int idx = tid; idx < 16*KP; idx += TPB) {
        int m = idx / KP, k = idx - m*KP;
        float v0 = 0.f, v1 = 0.f;
        if (k < 400) { v0 = Wg[(384+m)*400 + k]; if (m < 6) v1 = ws[CL_OFF + m*400 + k]; }
        else if (k == 400) v0 = ws[HINP_OFF + 384 + m];
        ((f16*)atile)[idx] = (f16)v0;
        ((f16*)atile)[16*KP + idx] = (f16)v1;
    }
    for (int idx = tid; idx < 480; idx += TPB) ((float*)dbuf)[idx] = 0.f;
    for (int idx = tid; idx < 96; idx += TPB) ((float*)frc)[idx] = 0.f;
    if (tid < 8) { rpl[0][tid][400] = (f16)1.f; rpl[1][tid][400] = (f16)1.f; }

    // ---- A-fragments in VGPRs (tiles 2w, 2w+1) ----
    half8 afA[13], afB[13];
    const int mtA = 2*wave, mtB = 2*wave + 1;
    {
        int mA = mtA*16 + col, mB = mtB*16 + col;
        #pragma unroll
        for (int kt = 0; kt < 13; ++kt) {
            int k0 = kt*32 + quad*8;
            afA[kt] = load_wfrag(Wg, ws, mA, k0);
            afB[kt] = load_wfrag(Wg, ws, mB, k0);
        }
    }

    // ---- state init: c = 19*x0 (x lives in accumulator scaled by (1-tau)/tau) ----
    // duplicate lanes (col>=8) mirror batch col-8 so their state stays bounded
    f32x4 c0, c1, c2;
    float caA[4], caB[4], caC[4];
    float msc[4] = {0.f, 0.f, 0.f, 0.f};
    float t1 = 1.f, t2 = 1.f, d1 = 0.f, d2 = 0.f;   // used by wave 9 lanes 0..7
    {
        int nA = mtA*16 + quad*4, nB = mtB*16 + quad*4, nC = 384 + quad*4;
        float rA[4], rB[4], rC[4];
        #pragma unroll
        for (int r = 0; r < 4; ++r) {
            float xa = sp[nA+r] + s*ws[XRAW_OFF + (nA+r)*8 + bcol];
            c0[r] = 19.f*xa; rA[r] = fmaxf(xa, 0.f);
            caA[r] = (5.f + gg[nA+r]) * (1.f/0.6968f);
            float xb = sp[nB+r] + s*ws[XRAW_OFF + (nB+r)*8 + bcol];
            c1[r] = 19.f*xb; rB[r] = fmaxf(xb, 0.f);
            caB[r] = (5.f + gg[nB+r]) * (1.f/0.6968f);
            float xc = sp[nC+r] + s*ws[XRAW_OFF + (nC+r)*8 + bcol];
            c2[r] = 19.f*xc; rC[r] = fmaxf(xc, 0.f);
            caC[r] = (5.f + gg[nC+r]) * (1.f/0.6968f);
        }
        if (col < 8) {
            store_r4(&rpl[0][col][mtA*16 + quad*4], rA[0], rA[1], rA[2], rA[3]);
            store_r4(&rpl[0][col][mtB*16 + quad*4], rB[0], rB[1], rB[2], rB[3]);
            if (wave == 10)
                store_r4(&rpl[0][col][384 + quad*4], rC[0], rC[1], rC[2], rC[3]);
        }
    }
    __syncthreads();

    const float MX[6] = {0.04f,-0.04f,0.f,0.f,0.028f,-0.035f};
    const float MY[6] = {0.f,0.f,0.025f,-0.025f,0.035f,-0.028f};

    // ---- step loop ----
    for (int i = 0; i < T; ++i) {
        const int p = i & 1;
        // wave 9: deferred arm ODE for step i-1 (reads frc[(i-1)&1], barrier-synced)
        if (wave == 9 && i > 0) {
            if (lane < 8) {
                const float* fr = frc[(i-1) & 1];
                float tq0 = 0.f, tq1 = 0.f;
                #pragma unroll
                for (int mm = 0; mm < 6; ++mm) {
                    float f = fr[mm*8 + lane];
                    tq0 = fmaf(f, MX[mm], tq0);
                    tq1 = fmaf(f, MY[mm], tq1);
                }
                float cc2 = cosf(t2), ss2 = sinf(t2);
                float M11 = A1C + 2.f*A2C*cc2;
                float M12 = A3C + A2C*cc2;
                float h = A2C * ss2;
                float C1v = -h * d2 * (2.f*d1 + d2);
                float C2v = h * d1 * d1;
                float rr1 = tq0 - C1v - (0.05f*d1 + 0.025f*d2);
                float rr2 = tq1 - C2v - (0.025f*d1 + 0.05f*d2);
                float det = M11*A3C - M12*M12;
                float dd1 = (A3C*rr1 - M12*rr2) / det;
                float dd2 = (M11*rr2 - M12*rr1) / det;
                t1 += DHC * d1; t2 += DHC * d2;
                d1 += DHC * dd1; d2 += DHC * dd2;
                float t12 = t1 + t2, d12 = d1 + d2;
                float c1v = cosf(t1), s1v = sinf(t1);
                float c12 = cosf(t12), s12 = sinf(t12);
                float4 o4;
                o4.x = L1C*c1v + L2C*c12;
                o4.y = L1C*s1v + L2C*s12;
                o4.z = -L1C*s1v*d1 - L2C*s12*d12;
                o4.w = L1C*c1v*d1 + L2C*c12*d12;
                obuf[(i-1) & 31][lane] = o4;
            }
            if ((i & 31) == 0) {   // flush steps i-32 .. i-1
                asm volatile("s_waitcnt lgkmcnt(0)" ::: "memory");
                #pragma unroll
                for (int k2 = 0; k2 < 4; ++k2) {
                    int idx = lane + (k2 << 6);
                    int so = idx >> 3, b = idx & 7;
                    *(float4*)(out + ((size_t)(i - 32 + so)*8 + b)*4) = obuf[so][b];
                }
            }
        }
        if (wave == 11) { c2[0] = 0.f; c2[1] = 0.f; c2[2] = 0.f; c2[3] = 0.f; }
        #pragma unroll
        for (int kt = 0; kt < 13; ++kt) {
            half8 b = *(const half8*)&rpl[p][bcol][kt*32 + quad*8];
            c0 = __builtin_amdgcn_mfma_f32_16x16x32_f16(afA[kt], b, c0, 0, 0, 0);
            c1 = __builtin_amdgcn_mfma_f32_16x16x32_f16(afB[kt], b, c1, 0, 0, 0);
            if (wave >= 10) {
                half8 a2 = *(const half8*)&atile[wave - 10][col][kt*32 + quad*8];
                c2 = __builtin_amdgcn_mfma_f32_16x16x32_f16(a2, b, c2, 0, 0, 0);
            }
        }
        const float tf = (float)(i + 1);
        const float et = __expf(tf * (-1.f/60.f)) - __expf(tf * (-1.f/6.f));
        {
            float rA[4], rB[4];
            #pragma unroll
            for (int r = 0; r < 4; ++r) {
                float ya = c0[r] + caA[r]*et;
                rA[r] = fmaxf(TAU_X*ya, 0.f); c0[r] = 0.95f*ya;
                float yb = c1[r] + caB[r]*et;
                rB[r] = fmaxf(TAU_X*yb, 0.f); c1[r] = 0.95f*yb;
            }
            if (col < 8) {
                store_r4(&rpl[p^1][col][mtA*16 + quad*4], rA[0], rA[1], rA[2], rA[3]);
                store_r4(&rpl[p^1][col][mtB*16 + quad*4], rB[0], rB[1], rB[2], rB[3]);
            }
        }
        if (wave == 10) {
            float rC[4];
            #pragma unroll
            for (int r = 0; r < 4; ++r) {
                float yc = c2[r] + caC[r]*et;
                rC[r] = fmaxf(TAU_X*yc, 0.f); c2[r] = 0.95f*yc;
            }
            if (col < 8)
                store_r4(&rpl[p^1][col][384 + quad*4], rC[0], rC[1], rC[2], rC[3]);
        }
        if (wave == 11 && col < 8) {
            int sl = i - (i/10)*10;
            #pragma unroll
            for (int r = 0; r < 4; ++r) {
                int m = quad*4 + r;
                if (m < 6) {
                    float mi = c2[r] * TAU_M;
                    float mnew = (mi > 0.f ? mi : 0.4f*mi) + 0.8f*msc[r];
                    msc[r] = mnew;
                    float delayed = dbuf[sl][m*8 + col];
                    dbuf[sl][m*8 + col] = mnew;
                    frc[i & 1][m*8 + col] = 40.f * fmaxf(delayed, 0.f);
                }
            }
        }
        __syncthreads();
    }
    // wave 9: final deferred ODE for step T-1 + residual flush
    if (wave == 9) {
        if (lane < 8) {
            const float* fr = frc[(T-1) & 1];
            float tq0 = 0.f, tq1 = 0.f;
            #pragma unroll
            for (int mm = 0; mm < 6; ++mm) {
                float f = fr[mm*8 + lane];
                tq0 = fmaf(f, MX[mm], tq0);
                tq1 = fmaf(f, MY[mm], tq1);
            }
            float cc2 = cosf(t2), ss2 = sinf(t2);
            float M11 = A1C + 2.f*A2C*cc2;
            float M12 = A3C + A2C*cc2;
            float h = A2C * ss2;
            float C1v = -h * d2 * (2.f*d1 + d2);
            float C2v = h * d1 * d1;
            float rr1 = tq0 - C1v - (0.05f*d1 + 0.025f*d2);
            float rr2 = tq1 - C2v - (0.025f*d1 + 0.05f*d2);
            float det = M11*A3C - M12*M12;
            float dd1 = (A3C*rr1 - M12*rr2) / det;
            float dd2 = (M11*rr2 - M12*rr1) / det;
            t1 += DHC * d1; t2 += DHC * d2;
            d1 += DHC * dd1; d2 += DHC * dd2;
            float t12 = t1 + t2, d12 = d1 + d2;
            float c1v = cosf(t1), s1v = sinf(t1);
            float c12 = cosf(t12), s12 = sinf(t12);
            float4 o4;
            o4.x = L1C*c1v + L2C*c12;
            o4.y = L1C*s1v + L2C*s12;
            o4.z = -L1C*s1v*d1 - L2C*s12*d12;
            o4.w = L1C*c1v*d1 + L2C*c12*d12;
            obuf[(T-1) & 31][lane] = o4;
        }
        asm volatile("s_waitcnt lgkmcnt(0)" ::: "memory");
        const int i0 = (T-1) & ~31;
        const int cnt = T - i0;           // 1..32 steps remaining
        for (int idx = lane; idx < cnt*8; idx += 64) {
            int so = idx >> 3, b = idx & 7;
            *(float4*)(out + ((size_t)(i0 + so)*8 + b)*4) = obuf[so][b];
        }
    }
}

extern "C" void kernel_launch(void* const* d_in, const int* in_sizes, int n_in,
                              void* d_out, int out_size, void* d_ws, size_t ws_size,
                              hipStream_t stream) {
    (void)in_sizes; (void)n_in; (void)out_size; (void)ws_size;
    const int*   Tp   = (const int*)d_in[0];
    const float* des  = (const float*)d_in[1];
    const float* W    = (const float*)d_in[3];
    const float* iw   = (const float*)d_in[4];
    const float* xp   = (const float*)d_in[5];
    const float* cp   = (const float*)d_in[6];
    const float* sp   = (const float*)d_in[7];
    const float* gg   = (const float*)d_in[8];
    const float* topo = (const float*)d_in[9];
    float* ws  = (float*)d_ws;
    float* out = (float*)d_out;

    k_pre1<<<NN, 64, 0, stream>>>(topo, xp, W, sp, iw, des, ws);
    k_pre2<<<1, 64, 0, stream>>>(cp, sp, ws);
    k_run<<<1, TPB, 0, stream>>>(Tp, W, sp, gg, ws, out);
}

// Round 2
// 2780.535 us; speedup vs baseline: 1.1235x; 1.1235x over previous
//
#include <hip/hip_runtime.h>
#include <math.h>

// Problem constants
#define NN 400
#define TPB 256          // 4 waves, 1 wave/SIMD, ~470 VGPR each (A-fragments register-resident)
#define KP 424           // padded K stride in fp16 elems

// workspace layout (32-bit indices)
#define XRAW_OFF 1024    // 3200 floats
#define HINP_OFF 4224    // 400 floats
#define CL_OFF   4624    // 2400 floats (projected readout c from k_pre2)

#define TAU_X 0.05f
#define TAU_M 0.2f
#define A1C 0.16f
#define A2C 0.048f
#define A3C 0.045f
#define DHC 0.001f
#define L1C 0.3f
#define L2C 0.33f

typedef unsigned long long ull;
typedef _Float16 f16;
typedef _Float16 __attribute__((ext_vector_type(8))) half8;
typedef float __attribute__((ext_vector_type(4))) f32x4;

// K1: xraw[n][b] = (top_obs @ xstars_prms)[n,b] + xstars_tar[b][n]; hinp[n] = spont[n]-(W@spont)[n]
__global__ __launch_bounds__(64) void k_pre1(const float* __restrict__ topo,
        const float* __restrict__ xp, const float* __restrict__ W,
        const float* __restrict__ sp, const float* __restrict__ iw,
        const float* __restrict__ des, float* __restrict__ ws)
{
    const int n = blockIdx.x, lane = threadIdx.x;
    float a0=0,a1=0,a2=0,a3=0,a4=0,a5=0,a6=0,a7=0, ah=0;
    for (int k = lane; k < NN; k += 64) {
        float to = topo[n*NN + k];
        float wv = W[n*NN + k];
        float s  = sp[k];
        const float* xr = xp + k*8;
        a0 = fmaf(to, xr[0], a0); a1 = fmaf(to, xr[1], a1);
        a2 = fmaf(to, xr[2], a2); a3 = fmaf(to, xr[3], a3);
        a4 = fmaf(to, xr[4], a4); a5 = fmaf(to, xr[5], a5);
        a6 = fmaf(to, xr[6], a6); a7 = fmaf(to, xr[7], a7);
        ah = fmaf(wv, s, ah);
    }
    #pragma unroll
    for (int m = 1; m < 64; m <<= 1) {
        a0 += __shfl_xor(a0, m, 64); a1 += __shfl_xor(a1, m, 64);
        a2 += __shfl_xor(a2, m, 64); a3 += __shfl_xor(a3, m, 64);
        a4 += __shfl_xor(a4, m, 64); a5 += __shfl_xor(a5, m, 64);
        a6 += __shfl_xor(a6, m, 64); a7 += __shfl_xor(a7, m, 64);
        ah += __shfl_xor(ah, m, 64);
    }
    if (lane == 0) {
        float av[8] = {a0,a1,a2,a3,a4,a5,a6,a7};
        float w0 = iw[n*10 + 0], w1 = iw[n*10 + 1];
        #pragma unroll
        for (int b = 0; b < 8; ++b) {
            float j0 = des[2*b]   - 0.25f;
            float j1 = des[2*b+1] - 0.25f;
            ws[XRAW_OFF + n*8 + b] = av[b] + j0*w0 + j1*w1;
        }
        ws[HINP_OFF + n] = sp[n] - ah;
    }
}

// K2: scale s, Gram solve (fp64), Q, Cl precompute
__global__ __launch_bounds__(64) void k_pre2(const float* __restrict__ cp,
        const float* __restrict__ sp, float* __restrict__ ws)
{
    __shared__ float part[99][65];
    __shared__ float red[99];
    const int lane = threadIdx.x;
    float Sxx[36], Sxs[8], Praw[48], Ps[6];
    float Sss = 0.f;
    #pragma unroll
    for (int q = 0; q < 36; ++q) Sxx[q] = 0.f;
    #pragma unroll
    for (int q = 0; q < 8; ++q) Sxs[q] = 0.f;
    #pragma unroll
    for (int q = 0; q < 48; ++q) Praw[q] = 0.f;
    #pragma unroll
    for (int q = 0; q < 6; ++q) Ps[q] = 0.f;

    for (int n = lane; n < NN; n += 64) {
        float xr[8];
        #pragma unroll
        for (int j = 0; j < 8; ++j) xr[j] = ws[XRAW_OFF + n*8 + j];
        float s = sp[n];
        int q = 0;
        #pragma unroll
        for (int i = 0; i < 8; ++i) {
            Sxs[i] = fmaf(xr[i], s, Sxs[i]);
            #pragma unroll
            for (int j = i; j < 8; ++j) { Sxx[q] = fmaf(xr[i], xr[j], Sxx[q]); ++q; }
        }
        Sss = fmaf(s, s, Sss);
        #pragma unroll
        for (int m = 0; m < 6; ++m) {
            float cv = cp[m*NN + n];
            #pragma unroll
            for (int j = 0; j < 8; ++j) Praw[m*8+j] = fmaf(cv, xr[j], Praw[m*8+j]);
            Ps[m] = fmaf(cv, s, Ps[m]);
        }
    }
    #pragma unroll
    for (int q = 0; q < 36; ++q) part[q][lane] = Sxx[q];
    #pragma unroll
    for (int j = 0; j < 8; ++j) part[36+j][lane] = Sxs[j];
    part[44][lane] = Sss;
    #pragma unroll
    for (int q = 0; q < 48; ++q) part[45+q][lane] = Praw[q];
    #pragma unroll
    for (int m = 0; m < 6; ++m) part[93+m][lane] = Ps[m];
    __syncthreads();
    for (int q = lane; q < 99; q += 64) {
        float acc = 0.f;
        for (int l = 0; l < 64; ++l) acc += part[q][l];
        red[q] = acc;
    }
    __syncthreads();
    if (lane == 0) {
        int IDX[8][8];
        { int q = 0; for (int i = 0; i < 8; ++i) for (int j = i; j < 8; ++j) { IDX[i][j]=q; IDX[j][i]=q; ++q; } }
        float sumsq = 0.f;
        for (int i = 0; i < 8; ++i) sumsq += red[IDX[i][i]];
        double s = sqrt(128.0 / (double)sumsq);   // z = N*B*0.2^2
        double Sssd = (double)red[44];
        double G[9][9];
        for (int i = 0; i < 8; ++i)
            for (int j = 0; j < 8; ++j)
                G[i][j] = s*s*(double)red[IDX[i][j]] + s*((double)red[36+i] + (double)red[36+j]) + Sssd;
        for (int i = 0; i < 8; ++i) { G[i][8] = G[8][i] = s*(double)red[36+i] + Sssd; }
        G[8][8] = Sssd;
        double A[9][18];
        for (int i = 0; i < 9; ++i)
            for (int j = 0; j < 9; ++j) { A[i][j] = G[i][j]; A[i][9+j] = (i==j) ? 1.0 : 0.0; }
        for (int col = 0; col < 9; ++col) {
            int piv = col; double mx = fabs(A[col][col]);
            for (int r = col+1; r < 9; ++r) { double v = fabs(A[r][col]); if (v > mx) { mx = v; piv = r; } }
            if (piv != col) for (int j = 0; j < 18; ++j) { double tt = A[col][j]; A[col][j] = A[piv][j]; A[piv][j] = tt; }
            double pv = A[col][col];
            for (int j = 0; j < 18; ++j) A[col][j] /= pv;
            for (int r = 0; r < 9; ++r) if (r != col) {
                double f = A[r][col];
                for (int j = 0; j < 18; ++j) A[r][j] -= f*A[col][j];
            }
        }
        for (int m = 0; m < 6; ++m) {
            double P[9];
            for (int j = 0; j < 8; ++j) P[j] = s*(double)red[45 + m*8 + j] + (double)red[93+m];
            P[8] = (double)red[93+m];
            for (int j = 0; j < 9; ++j) {
                double qv = 0;
                for (int l = 0; l < 9; ++l) qv += P[l]*A[l][9+j];
                ws[2 + m*9 + j] = (float)qv;
            }
        }
        ws[1] = (float)s;
    }
    __syncthreads();
    // Cl[m][n] = cp[m][n] - s*(Q[m,:8].xraw[n,:]) - sp[n]*sum(Q[m,:])
    {
        float s = ws[1];
        for (int idx = lane; idx < 6*NN; idx += 64) {
            int m = idx / NN, n = idx - m*NN;
            float acc = 0.f, sq = 0.f;
            #pragma unroll
            for (int j = 0; j < 8; ++j) {
                float q = ws[2 + m*9 + j];
                acc = fmaf(q, ws[XRAW_OFF + n*8 + j], acc);
                sq += q;
            }
            sq += ws[2 + m*9 + 8];
            ws[CL_OFF + idx] = cp[idx] - s*acc - sp[n]*sq;
        }
    }
}

// A-fragment loader: W[m][k0..k0+7] fp32 -> fp16; k=400 carries h_inp (r row 400 == 1)
__device__ __forceinline__ half8 load_wfrag(const float* __restrict__ Wg,
        const float* __restrict__ ws, int m, int k0)
{
    half8 a;
    if (k0 + 8 <= 400) {
        float4 x0 = *(const float4*)(Wg + m*400 + k0);
        float4 x1 = *(const float4*)(Wg + m*400 + k0 + 4);
        a[0]=(f16)x0.x; a[1]=(f16)x0.y; a[2]=(f16)x0.z; a[3]=(f16)x0.w;
        a[4]=(f16)x1.x; a[5]=(f16)x1.y; a[6]=(f16)x1.z; a[7]=(f16)x1.w;
    } else {
        #pragma unroll
        for (int j = 0; j < 8; ++j) {
            int k = k0 + j;
            float v = 0.f;
            if (k < 400) v = Wg[m*400 + k];
            else if (k == 400) v = ws[HINP_OFF + m];
            a[j] = (f16)v;
        }
    }
    return a;
}

// Muscle-Cl fragment: rows = muscle index (only 0..5 real), no bias at k=400
__device__ __forceinline__ half8 load_clfrag(const float* __restrict__ cl, int m, int k0)
{
    half8 a;
    #pragma unroll
    for (int j = 0; j < 8; ++j) {
        int k = k0 + j;
        float v = (m < 6 && k < 400) ? cl[m*400 + k] : 0.f;
        a[j] = (f16)v;
    }
    return a;
}

__device__ __forceinline__ void store_r4(f16* dst, float r0, float r1, float r2, float r3) {
    union { f16 h[4]; ull u; } pk;
    pk.h[0] = (f16)r0; pk.h[1] = (f16)r1; pk.h[2] = (f16)r2; pk.h[3] = (f16)r3;
    *(ull*)dst = pk.u;
}

// one Euler step of the 2-link arm + kinematics; lanes 0..7 (one per batch)
__device__ __forceinline__ void arm_step_ode(const float* __restrict__ fr, int lane,
        float& t1, float& t2, float& d1, float& d2, float4& o4)
{
    const float MX[6] = {0.04f,-0.04f,0.f,0.f,0.028f,-0.035f};
    const float MY[6] = {0.f,0.f,0.025f,-0.025f,0.035f,-0.028f};
    float tq0 = 0.f, tq1 = 0.f;
    #pragma unroll
    for (int mm = 0; mm < 6; ++mm) {
        float f = fr[mm*8 + lane];
        tq0 = fmaf(f, MX[mm], tq0);
        tq1 = fmaf(f, MY[mm], tq1);
    }
    float cc2 = cosf(t2), ss2 = sinf(t2);
    float M11 = A1C + 2.f*A2C*cc2;
    float M12 = A3C + A2C*cc2;
    float h = A2C * ss2;
    float C1v = -h * d2 * (2.f*d1 + d2);
    float C2v = h * d1 * d1;
    float rr1 = tq0 - C1v - (0.05f*d1 + 0.025f*d2);
    float rr2 = tq1 - C2v - (0.025f*d1 + 0.05f*d2);
    float det = M11*A3C - M12*M12;
    float dd1 = (A3C*rr1 - M12*rr2) / det;
    float dd2 = (M11*rr2 - M12*rr1) / det;
    t1 += DHC * d1; t2 += DHC * d2;
    d1 += DHC * dd1; d2 += DHC * dd2;
    float t12 = t1 + t2, d12 = d1 + d2;
    float c1v = cosf(t1), s1v = sinf(t1);
    float c12 = cosf(t12), s12 = sinf(t12);
    o4.x = L1C*c1v + L2C*c12;
    o4.y = L1C*s1v + L2C*s12;
    o4.z = -L1C*s1v*d1 - L2C*s12*d12;
    o4.w = L1C*c1v*d1 + L2C*c12*d12;
}

// K3: whole recurrence on ONE CU via MFMA; 4 fat waves (1 per SIMD), 512-reg budget.
// Tile map (16-row M-tiles, K=424 incl. bias row 400 = h_inp):
//   wave0: W tiles 0..6   wave1: W tiles 7..13
//   wave2: W tiles 14..19 + deferred arm ODE + out-ring flush
//   wave3: W tiles 20..24 + muscle-Cl tile (slot 5, register-resident) + muscle state
// B (r-plane) is read once per kt per wave and reused across all its tiles:
// 52 ds_read_b128/step total (was 182). Single barrier per step.
__global__ __launch_bounds__(TPB, 1) void k_run(const int* __restrict__ Tp,
        const float* __restrict__ Wg, const float* __restrict__ sp,
        const float* __restrict__ gg, float* __restrict__ ws,
        float* __restrict__ out)
{
    __shared__ __align__(16) f16 rpl[2][8][KP];     // r planes [batch(8)][neuron k(424)]
    __shared__ float dbuf[10][48];                  // muscle delay ring (wave3)
    __shared__ float frc[2][48];                    // double-buffered: w3 writes, w2 reads
    __shared__ float4 obuf[32][8];                  // 32-step cart out-ring (wave2)

    const int tid = threadIdx.x;
    const int T = *Tp;
    const int wave = tid >> 6, lane = tid & 63;
    const int quad = lane >> 4, col = lane & 15;
    const int bcol = col & 7;
    const float s = ws[1];

    // ---- LDS init ----
    for (int idx = tid; idx < 2*8*KP; idx += TPB) ((f16*)rpl)[idx] = (f16)0.f;
    for (int idx = tid; idx < 480; idx += TPB) ((float*)dbuf)[idx] = 0.f;
    for (int idx = tid; idx < 96; idx += TPB) ((float*)frc)[idx] = 0.f;
    __syncthreads();
    if (tid < 8) { rpl[0][tid][400] = (f16)1.f; rpl[1][tid][400] = (f16)1.f; }

    // ---- tile assignment ----
    const int base = wave*7 - (wave == 3 ? 1 : 0);   // 0,7,14,20
    const int nW   = (wave < 2) ? 7 : (wave == 2 ? 6 : 5);

    // ---- A-fragments in registers: af[t][kt] ----
    half8 af[7][13];
    #pragma unroll
    for (int t = 0; t < 7; ++t) {
        #pragma unroll
        for (int kt = 0; kt < 13; ++kt) {
            int k0 = kt*32 + quad*8;
            if (t < nW) {
                af[t][kt] = load_wfrag(Wg, ws, (base + t)*16 + col, k0);
            } else if (wave == 3 && t == 5) {
                af[t][kt] = load_clfrag(ws + CL_OFF, col, k0);
            } else {
                half8 z;
                #pragma unroll
                for (int j = 0; j < 8; ++j) z[j] = (f16)0.f;
                af[t][kt] = z;
            }
        }
    }

    // ---- state init: acc = 19*x0 (x lives in accumulator scaled by (1-tau)/tau) ----
    f32x4 acc[7];
    float ca[7][4];
    float msc[4] = {0.f, 0.f, 0.f, 0.f};
    float t1 = 1.f, t2 = 1.f, d1 = 0.f, d2 = 0.f;   // wave2 lanes 0..7
    #pragma unroll
    for (int t = 0; t < 7; ++t) {
        #pragma unroll
        for (int r = 0; r < 4; ++r) { acc[t][r] = 0.f; ca[t][r] = 0.f; }
    }
    #pragma unroll
    for (int t = 0; t < 7; ++t) {
        if (t < nW) {
            int n0 = (base + t)*16 + quad*4;
            float rr[4];
            #pragma unroll
            for (int r = 0; r < 4; ++r) {
                float xa = sp[n0+r] + s*ws[XRAW_OFF + (n0+r)*8 + bcol];
                acc[t][r] = 19.f*xa;
                rr[r] = fmaxf(xa, 0.f);
                ca[t][r] = (5.f + gg[n0+r]) * (1.f/0.6968f);
            }
            if (col < 8)
                store_r4(&rpl[0][col][(base + t)*16 + quad*4], rr[0], rr[1], rr[2], rr[3]);
        }
    }
    __syncthreads();

    // ---- step loop ----
    for (int i = 0; i < T; ++i) {
        const int p = i & 1;
        // wave2: deferred arm ODE for step i-1 (frc[(i-1)&1] written by wave3 last step)
        if (wave == 2 && i > 0) {
            if (lane < 8) {
                float4 o4;
                arm_step_ode(frc[(i-1) & 1], lane, t1, t2, d1, d2, o4);
                obuf[(i-1) & 31][lane] = o4;
            }
            if ((i & 31) == 0) {   // flush steps i-32 .. i-1
                asm volatile("s_waitcnt lgkmcnt(0)" ::: "memory");
                #pragma unroll
                for (int k2 = 0; k2 < 4; ++k2) {
                    int idx = lane + (k2 << 6);
                    int so = idx >> 3, b = idx & 7;
                    *(float4*)(out + ((size_t)(i - 32 + so)*8 + b)*4) = obuf[so][b];
                }
            }
        }
        if (wave == 3) { acc[5][0]=0.f; acc[5][1]=0.f; acc[5][2]=0.f; acc[5][3]=0.f; }

        #pragma unroll
        for (int kt = 0; kt < 13; ++kt) {
            half8 b = *(const half8*)&rpl[p][bcol][kt*32 + quad*8];
            #pragma unroll
            for (int t = 0; t < 7; ++t)
                acc[t] = __builtin_amdgcn_mfma_f32_16x16x32_f16(af[t][kt], b, acc[t], 0, 0, 0);
        }

        const float tf = (float)(i + 1);
        const float et = __expf(tf * (-1.f/60.f)) - __expf(tf * (-1.f/6.f));
        #pragma unroll
        for (int t = 0; t < 7; ++t) {
            if (t < nW) {
                float rr[4];
                #pragma unroll
                for (int r = 0; r < 4; ++r) {
                    float ya = acc[t][r] + ca[t][r]*et;
                    rr[r] = fmaxf(TAU_X*ya, 0.f);
                    acc[t][r] = 0.95f*ya;
                }
                if (col < 8)
                    store_r4(&rpl[p^1][col][(base + t)*16 + quad*4], rr[0], rr[1], rr[2], rr[3]);
            }
        }
        // wave3: muscle update from Cl-tile accumulator (slot 5)
        if (wave == 3 && col < 8) {
            int sl = i - (i/10)*10;
            #pragma unroll
            for (int r = 0; r < 4; ++r) {
                int m = quad*4 + r;
                if (m < 6) {
                    float mi = acc[5][r] * TAU_M;
                    float mnew = (mi > 0.f ? mi : 0.4f*mi) + 0.8f*msc[r];
                    msc[r] = mnew;
                    float delayed = dbuf[sl][m*8 + col];
                    dbuf[sl][m*8 + col] = mnew;
                    frc[i & 1][m*8 + col] = 40.f * fmaxf(delayed, 0.f);
                }
            }
        }
        __syncthreads();
    }

    // wave2: final deferred ODE for step T-1 + residual flush
    if (wave == 2) {
        if (lane < 8) {
            float4 o4;
            arm_step_ode(frc[(T-1) & 1], lane, t1, t2, d1, d2, o4);
            obuf[(T-1) & 31][lane] = o4;
        }
        asm volatile("s_waitcnt lgkmcnt(0)" ::: "memory");
        const int i0 = (T-1) & ~31;
        const int cnt = T - i0;           // 1..32 steps remaining
        for (int idx = lane; idx < cnt*8; idx += 64) {
            int so = idx >> 3, b = idx & 7;
            *(float4*)(out + ((size_t)(i0 + so)*8 + b)*4) = obuf[so][b];
        }
    }
}

extern "C" void kernel_launch(void* const* d_in, const int* in_sizes, int n_in,
                              void* d_out, int out_size, void* d_ws, size_t ws_size,
                              hipStream_t stream) {
    (void)in_sizes; (void)n_in; (void)out_size; (void)ws_size;
    const int*   Tp   = (const int*)d_in[0];
    const float* des  = (const float*)d_in[1];
    const float* W    = (const float*)d_in[3];
    const float* iw   = (const float*)d_in[4];
    const float* xp   = (const float*)d_in[5];
    const float* cp   = (const float*)d_in[6];
    const float* sp   = (const float*)d_in[7];
    const float* gg   = (const float*)d_in[8];
    const float* topo = (const float*)d_in[9];
    float* ws  = (float*)d_ws;
    float* out = (float*)d_out;

    k_pre1<<<NN, 64, 0, stream>>>(topo, xp, W, sp, iw, des, ws);
    k_pre2<<<1, 64, 0, stream>>>(cp, sp, ws);
    k_run<<<1, TPB, 0, stream>>>(Tp, W, sp, gg, ws, out);
}